// Round 5
// baseline (224.896 us; speedup 1.0000x reference)
//
#include <hip/hip_runtime.h>

#define LSEQ 512
#define BATCH 1024
#define T 48
#define TP 49          // padded LDS row (49 odd -> conflict-free across lanes)
#define CHUNK 8
#define NCH (LSEQ / CHUNK)   // 64 chunks cover t = 1..512 (512 guarded off)

static __device__ __forceinline__ float bcast_lane0(float x) {
    return __int_as_float(__builtin_amdgcn_readfirstlane(__float_as_int(x)));
}
static __device__ __forceinline__ float rl(float x, int i) {
    return __int_as_float(__builtin_amdgcn_readlane(__float_as_int(x), i));
}
static __device__ __forceinline__ float fast_rcp(float x) {
#if __has_builtin(__builtin_amdgcn_rcpf)
    return __builtin_amdgcn_rcpf(x);
#else
    return 1.0f / x;
#endif
}

// One forward step in linear space. Invariant: alpha_t[j] = C + log w[j], w[0]=1.
//   S[j]  = sum_i w[i] * E[i][j]        (48 fmac, w_i broadcast via readlane)
//   w'[j] = exp(em[j]-em[0]) * S[j]/S[0];   C += em[0] + log(S[0])
static __device__ __forceinline__ void crf_step(
    float& w, float& C, float em, int mk, int tt, bool valid,
    const float* __restrict__ Ejv)
{
    const float em0 = bcast_lane0(em);
    const float e   = __expf(em - em0);        // off the w->S->w critical path
    float s0 = 0.f, s1 = 0.f, s2 = 0.f, s3 = 0.f;
    #pragma unroll
    for (int i = 0; i < T; i += 4) {
        s0 = __builtin_fmaf(rl(w, i + 0), Ejv[i + 0], s0);
        s1 = __builtin_fmaf(rl(w, i + 1), Ejv[i + 1], s1);
        s2 = __builtin_fmaf(rl(w, i + 2), Ejv[i + 2], s2);
        s3 = __builtin_fmaf(rl(w, i + 3), Ejv[i + 3], s3);
    }
    const float S    = (s0 + s1) + (s2 + s3);
    const float S0   = bcast_lane0(S);
    const float rs   = fast_rcp(S0);
    const float lg   = __logf(S0);             // wave-uniform, off w-path
    const float wnew = (e * rs) * S;
    const bool  upd  = (mk != 0) && (tt < LSEQ);
    w = (upd && valid) ? wnew : w;             // dummy lanes stay 0
    C = upd ? (C + em0 + lg) : C;
}

// ---------------------------------------------------------------------------
// Kernel 1: forward algorithm (denominator). One wave per batch; lane j owns
// state j. E = exp(trans) lives in LDS [j][i] (pad 49 -> conflict-free
// ds_read2); emissions/mask double-buffered in 8-deep static register chunks.
// No per-step global loads on the critical path; no barriers after init.
// ---------------------------------------------------------------------------
__global__ __launch_bounds__(256, 1) void crf_forward(
    const float* __restrict__ emissions,      // (L,B,T)
    const int* __restrict__ mask,             // (L,B) bool->int32
    const float* __restrict__ start_tr,       // (T)
    const float* __restrict__ end_tr,         // (T)
    const float* __restrict__ trans,          // (T,T)
    float* __restrict__ denom_out)            // (B)
{
    __shared__ float Elds[T * TP];            // Elds[j*TP+i] = exp(trans[i][j])
    const int tid = threadIdx.x;
    #pragma unroll
    for (int r = 0; r < (T * T + 255) / 256; ++r) {
        int g = tid + r * 256;
        if (g < T * T) {
            int i = g / T, j = g % T;
            Elds[j * TP + i] = __expf(trans[g]);
        }
    }
    __syncthreads();

    const int wave = tid >> 6, lane = tid & 63;
    const int b    = blockIdx.x * 4 + wave;
    const bool valid = (lane < T);
    const int jc   = valid ? lane : (T - 1);
    const unsigned ebase = (unsigned)(jc * TP);

    const float* emb = emissions + (size_t)b * T + jc;   // + t*BATCH*T per step
    const int*   mkb = mask + b;

    // init: alpha0 = start + em[0]; w = exp(alpha0 - alpha0[0]); C = alpha0[0]
    const float a0 = start_tr[jc] + emb[0];
    const float A0 = bcast_lane0(a0);
    float w = valid ? __expf(a0 - A0) : 0.f;
    float C = A0;

    // double-buffered 8-deep prefetch, all indices compile-time (no scratch)
    float emA[CHUNK], emB[CHUNK];
    int   mkA[CHUNK], mkB[CHUNK];
    #pragma unroll
    for (int u = 0; u < CHUNK; ++u) {
        const int tt = 1 + u;
        emA[u] = emb[(size_t)tt * (BATCH * T)];
        mkA[u] = mkb[tt * BATCH];
    }

    for (int c = 0; c < NCH; c += 2) {
        {   // issue chunk c+1 -> B
            const int tB = 1 + (c + 1) * CHUNK;
            #pragma unroll
            for (int u = 0; u < CHUNK; ++u) {
                int tt = tB + u; if (tt > LSEQ - 1) tt = LSEQ - 1;
                emB[u] = emb[(size_t)tt * (BATCH * T)];
                mkB[u] = mkb[tt * BATCH];
            }
        }
        {   // compute chunk c from A
            const int t0 = 1 + c * CHUNK;
            #pragma unroll
            for (int u = 0; u < CHUNK; ++u) {
                unsigned eb = ebase;
                asm volatile("" : "+v"(eb));   // defeat LICM: re-read E from LDS
                crf_step(w, C, emA[u], mkA[u], t0 + u, valid, &Elds[eb]);
            }
        }
        {   // issue chunk c+2 -> A
            const int tA = 1 + (c + 2) * CHUNK;
            #pragma unroll
            for (int u = 0; u < CHUNK; ++u) {
                int tt = tA + u; if (tt > LSEQ - 1) tt = LSEQ - 1;
                emA[u] = emb[(size_t)tt * (BATCH * T)];
                mkA[u] = mkb[tt * BATCH];
            }
        }
        {   // compute chunk c+1 from B
            const int t0 = 1 + (c + 1) * CHUNK;
            #pragma unroll
            for (int u = 0; u < CHUNK; ++u) {
                unsigned eb = ebase;
                asm volatile("" : "+v"(eb));
                crf_step(w, C, emB[u], mkB[u], t0 + u, valid, &Elds[eb]);
            }
        }
    }

    // denominator = C + log( sum_j w[j] * exp(end[j]) )
    float v = valid ? (w * __expf(end_tr[jc])) : 0.f;
    #pragma unroll
    for (int off = 32; off > 0; off >>= 1) v += __shfl_xor(v, off);
    if (lane == 0) denom_out[b] = C + __logf(v);
}

// ---------------------------------------------------------------------------
// Kernel 2: numerator partial sums over t-chunks (runtime chunk count).
// ---------------------------------------------------------------------------
__global__ __launch_bounds__(256) void crf_score_partial(
    const float* __restrict__ emissions,
    const int* __restrict__ tags,             // (L,B)
    const int* __restrict__ mask,             // (L,B)
    const float* __restrict__ trans,          // (T,T)
    float* __restrict__ part,                 // (nchunk, B)
    int* __restrict__ cnt,                    // (nchunk, B)
    int csz)
{
    const int gid = blockIdx.x * blockDim.x + threadIdx.x;
    const int b = gid & (BATCH - 1);
    const int c = gid >> 10;
    const int t0 = c * csz;
    const int t1 = t0 + csz;

    float sc = 0.f;
    int ct = 0;
    const int tstart = (t0 == 0) ? 1 : t0;
    if (t0 == 0) ct += mask[b] ? 1 : 0;       // t = 0 contributes to count only

    int tag_prev = tags[(tstart - 1) * BATCH + b];
    for (int t = tstart; t < t1; ++t) {
        const int tag = tags[t * BATCH + b];
        const int mt = mask[t * BATCH + b];
        if (mt) {
            sc += trans[tag_prev * T + tag]
                + emissions[((size_t)t * BATCH + b) * T + tag];
            ct += 1;
        }
        tag_prev = tag;                       // raw previous tag, per reference
    }
    part[gid] = sc;
    cnt[gid] = ct;
}

// ---------------------------------------------------------------------------
// Kernel 3: combine partials + start/end terms, subtract denominator, mean.
// ---------------------------------------------------------------------------
__global__ __launch_bounds__(1024) void crf_combine(
    const float* __restrict__ emissions,
    const int* __restrict__ tags,
    const float* __restrict__ start_tr,
    const float* __restrict__ end_tr,
    const float* __restrict__ part,
    const int* __restrict__ cnt,
    const float* __restrict__ denom,
    float* __restrict__ out,
    int nchunk)
{
    const int b = threadIdx.x;

    const int tag0 = tags[b];
    float sc = start_tr[tag0] + emissions[(size_t)b * T + tag0];
    int ct = 0;
    for (int c = 0; c < nchunk; ++c) {
        sc += part[c * BATCH + b];
        ct += cnt[c * BATCH + b];
    }
    if (ct < 1) ct = 1;                        // guard (mask all-zero)
    const int last_tag = tags[(ct - 1) * BATCH + b];
    sc += end_tr[last_tag];

    const float llh = sc - denom[b];

    __shared__ float red[1024];
    red[b] = llh;
    __syncthreads();
    #pragma unroll
    for (int s = 512; s > 0; s >>= 1) {
        if (b < s) red[b] += red[b + s];
        __syncthreads();
    }
    if (b == 0) out[0] = red[0] / (float)BATCH;
}

extern "C" void kernel_launch(void* const* d_in, const int* in_sizes, int n_in,
                              void* d_out, int out_size, void* d_ws, size_t ws_size,
                              hipStream_t stream) {
    const float* emissions        = (const float*)d_in[0];
    const int* tags               = (const int*)d_in[1];
    const int* mask               = (const int*)d_in[2];
    const float* start_tr         = (const float*)d_in[3];
    const float* end_tr           = (const float*)d_in[4];
    const float* trans            = (const float*)d_in[5];
    float* out                    = (float*)d_out;

    // scale numerator chunk count to available workspace
    const int nchunk = (ws_size >= (size_t)(BATCH * 4 + 32 * BATCH * 8 + 64)) ? 32 : 8;
    const int csz    = LSEQ / nchunk;

    float* denom = (float*)d_ws;                  // B floats
    float* part  = denom + BATCH;                 // nchunk*B floats
    int*   cnt   = (int*)(part + nchunk * BATCH); // nchunk*B ints

    crf_forward<<<256, 256, 0, stream>>>(emissions, mask, start_tr, end_tr, trans, denom);
    crf_score_partial<<<nchunk * BATCH / 256, 256, 0, stream>>>(
        emissions, tags, mask, trans, part, cnt, csz);
    crf_combine<<<1, 1024, 0, stream>>>(emissions, tags, start_tr, end_tr,
                                        part, cnt, denom, out, nchunk);
}

// Round 6
// 218.490 us; speedup vs baseline: 1.0293x; 1.0293x over previous
//
#include <hip/hip_runtime.h>

#define LSEQ 512
#define BATCH 1024
#define T 48
#define CHUNK 8
#define NCH (LSEQ / CHUNK)   // 64 chunks cover t = 1..512 (t=512 masked off)

static __device__ __forceinline__ float bcast_lane0(float x) {
    return __int_as_float(__builtin_amdgcn_readfirstlane(__float_as_int(x)));
}
static __device__ __forceinline__ float rl(float x, int i) {
    return __int_as_float(__builtin_amdgcn_readlane(__float_as_int(x), i));
}
static __device__ __forceinline__ float fast_rcp(float x) {
#if __has_builtin(__builtin_amdgcn_rcpf)
    return __builtin_amdgcn_rcpf(x);
#else
    return 1.0f / x;
#endif
}

// zero-instruction register pins: forces operands to live in VGPRs here
#define PIN4(a,b,c,d) asm volatile("" : "+v"(a), "+v"(b), "+v"(c), "+v"(d))
#define PIN_E(E) do { \
    PIN4(E[ 0],E[ 1],E[ 2],E[ 3]); PIN4(E[ 4],E[ 5],E[ 6],E[ 7]); \
    PIN4(E[ 8],E[ 9],E[10],E[11]); PIN4(E[12],E[13],E[14],E[15]); \
    PIN4(E[16],E[17],E[18],E[19]); PIN4(E[20],E[21],E[22],E[23]); \
    PIN4(E[24],E[25],E[26],E[27]); PIN4(E[28],E[29],E[30],E[31]); \
    PIN4(E[32],E[33],E[34],E[35]); PIN4(E[36],E[37],E[38],E[39]); \
    PIN4(E[40],E[41],E[42],E[43]); PIN4(E[44],E[45],E[46],E[47]); \
} while (0)

// One forward step in linear space. Invariant: alpha_t[j] = C + log w[j], w[0]=1.
//   S[j]  = sum_i w[i] * E[i][j]     (48 fmac; w_i broadcast via readlane->SGPR)
//   w'[j] = exp(em[j]-em[0]) * S[j]/S[0];   C += em[0] + log(S[0])
static __device__ __forceinline__ void crf_step(
    float& w, float& C, float em, int mk, bool valid, const float* E)
{
    const float em0 = bcast_lane0(em);
    const float e   = __expf(em - em0);        // off the w->S->w critical path
    float s0 = 0.f, s1 = 0.f, s2 = 0.f, s3 = 0.f;
    #pragma unroll
    for (int i = 0; i < T; i += 4) {
        s0 = __builtin_fmaf(rl(w, i + 0), E[i + 0], s0);
        s1 = __builtin_fmaf(rl(w, i + 1), E[i + 1], s1);
        s2 = __builtin_fmaf(rl(w, i + 2), E[i + 2], s2);
        s3 = __builtin_fmaf(rl(w, i + 3), E[i + 3], s3);
    }
    const float S    = (s0 + s1) + (s2 + s3);
    const float S0   = bcast_lane0(S);
    const float rs   = fast_rcp(S0);
    const float lg   = __logf(S0);             // wave-uniform, off w-path
    const float wnew = (e * rs) * S;
    const bool  upd  = (mk != 0);
    w = (upd && valid) ? wnew : w;             // dummy lanes stay 0
    C = upd ? (C + em0 + lg) : C;
}

// ---------------------------------------------------------------------------
// Kernel 1: forward algorithm (denominator). One wave per batch; lane j owns
// state j. E[i] = exp(trans[i][j]) lives in 48 PINNED VGPRs (asm-constrained
// each chunk so the allocator cannot spill/rematerialize it). Emissions/mask
// double-buffered in 8-deep static register chunks; uniform t-offset -> SGPR
// base arithmetic. No LDS, no barriers, no global loads on the w-critical-path.
// ---------------------------------------------------------------------------
__global__ __launch_bounds__(256, 1) void crf_forward(
    const float* __restrict__ emissions,      // (L,B,T)
    const int* __restrict__ mask,             // (L,B) bool->int32
    const float* __restrict__ start_tr,       // (T)
    const float* __restrict__ end_tr,         // (T)
    const float* __restrict__ trans,          // (T,T)
    float* __restrict__ denom_out)            // (B)
{
    const int tid  = threadIdx.x;
    const int wave = tid >> 6, lane = tid & 63;
    const int b    = blockIdx.x * 4 + wave;
    const bool valid = (lane < T);
    const int jc   = valid ? lane : (T - 1);

    // E column in registers: E[i] = exp(trans[i][jc]); coalesced per i
    float E[T];
    #pragma unroll
    for (int i = 0; i < T; ++i) E[i] = __expf(trans[i * T + jc]);

    const float* emb = emissions + (size_t)b * T + jc;   // + t*BATCH*T per step
    const int*   mkb = mask + b;

    // init: alpha0 = start + em[0]; w = exp(alpha0 - alpha0[0]); C = alpha0[0]
    const float a0 = start_tr[jc] + emb[0];
    const float A0 = bcast_lane0(a0);
    float w = valid ? __expf(a0 - A0) : 0.f;
    float C = A0;

    // double-buffered 8-deep prefetch, all indices compile-time (no scratch)
    float emA[CHUNK], emB[CHUNK];
    int   mkA[CHUNK], mkB[CHUNK];
    #pragma unroll
    for (int u = 0; u < CHUNK; ++u) {
        const int tt = 1 + u;
        emA[u] = emb[(size_t)tt * (BATCH * T)];
        mkA[u] = mkb[tt * BATCH];
    }

    for (int c = 0; c < NCH; c += 2) {
        PIN_E(E);   // keep E resident in VGPRs across the whole loop
        {   // issue chunk c+1 -> B
            const int tB = 1 + (c + 1) * CHUNK;
            #pragma unroll
            for (int u = 0; u < CHUNK; ++u) {
                const int tt = tB + u;
                const bool ok = (tt <= LSEQ - 1);
                const int tc = ok ? tt : (LSEQ - 1);
                emB[u] = emb[(size_t)tc * (BATCH * T)];
                mkB[u] = ok ? mkb[tc * BATCH] : 0;
            }
        }
        {   // compute chunk c from A
            #pragma unroll
            for (int u = 0; u < CHUNK; ++u)
                crf_step(w, C, emA[u], mkA[u], valid, E);
        }
        {   // issue chunk c+2 -> A
            const int tA = 1 + (c + 2) * CHUNK;
            #pragma unroll
            for (int u = 0; u < CHUNK; ++u) {
                const int tt = tA + u;
                const bool ok = (tt <= LSEQ - 1);
                const int tc = ok ? tt : (LSEQ - 1);
                emA[u] = emb[(size_t)tc * (BATCH * T)];
                mkA[u] = ok ? mkb[tc * BATCH] : 0;
            }
        }
        {   // compute chunk c+1 from B
            #pragma unroll
            for (int u = 0; u < CHUNK; ++u)
                crf_step(w, C, emB[u], mkB[u], valid, E);
        }
    }

    // denominator = C + log( sum_j w[j] * exp(end[j]) )
    float v = valid ? (w * __expf(end_tr[jc])) : 0.f;
    #pragma unroll
    for (int off = 32; off > 0; off >>= 1) v += __shfl_xor(v, off);
    if (lane == 0) denom_out[b] = C + __logf(v);
}

// ---------------------------------------------------------------------------
// Kernel 2: numerator partial sums over t-chunks (runtime chunk count).
// ---------------------------------------------------------------------------
__global__ __launch_bounds__(256) void crf_score_partial(
    const float* __restrict__ emissions,
    const int* __restrict__ tags,             // (L,B)
    const int* __restrict__ mask,             // (L,B)
    const float* __restrict__ trans,          // (T,T)
    float* __restrict__ part,                 // (nchunk, B)
    int* __restrict__ cnt,                    // (nchunk, B)
    int csz)
{
    const int gid = blockIdx.x * blockDim.x + threadIdx.x;
    const int b = gid & (BATCH - 1);
    const int c = gid >> 10;
    const int t0 = c * csz;
    const int t1 = t0 + csz;

    float sc = 0.f;
    int ct = 0;
    const int tstart = (t0 == 0) ? 1 : t0;
    if (t0 == 0) ct += mask[b] ? 1 : 0;       // t = 0 contributes to count only

    int tag_prev = tags[(tstart - 1) * BATCH + b];
    for (int t = tstart; t < t1; ++t) {
        const int tag = tags[t * BATCH + b];
        const int mt = mask[t * BATCH + b];
        if (mt) {
            sc += trans[tag_prev * T + tag]
                + emissions[((size_t)t * BATCH + b) * T + tag];
            ct += 1;
        }
        tag_prev = tag;                       // raw previous tag, per reference
    }
    part[gid] = sc;
    cnt[gid] = ct;
}

// ---------------------------------------------------------------------------
// Kernel 3: combine partials + start/end terms, subtract denominator, mean.
// ---------------------------------------------------------------------------
__global__ __launch_bounds__(1024) void crf_combine(
    const float* __restrict__ emissions,
    const int* __restrict__ tags,
    const float* __restrict__ start_tr,
    const float* __restrict__ end_tr,
    const float* __restrict__ part,
    const int* __restrict__ cnt,
    const float* __restrict__ denom,
    float* __restrict__ out,
    int nchunk)
{
    const int b = threadIdx.x;

    const int tag0 = tags[b];
    float sc = start_tr[tag0] + emissions[(size_t)b * T + tag0];
    int ct = 0;
    for (int c = 0; c < nchunk; ++c) {
        sc += part[c * BATCH + b];
        ct += cnt[c * BATCH + b];
    }
    if (ct < 1) ct = 1;                        // guard (mask all-zero)
    const int last_tag = tags[(ct - 1) * BATCH + b];
    sc += end_tr[last_tag];

    const float llh = sc - denom[b];

    __shared__ float red[1024];
    red[b] = llh;
    __syncthreads();
    #pragma unroll
    for (int s = 512; s > 0; s >>= 1) {
        if (b < s) red[b] += red[b + s];
        __syncthreads();
    }
    if (b == 0) out[0] = red[0] / (float)BATCH;
}

extern "C" void kernel_launch(void* const* d_in, const int* in_sizes, int n_in,
                              void* d_out, int out_size, void* d_ws, size_t ws_size,
                              hipStream_t stream) {
    const float* emissions        = (const float*)d_in[0];
    const int* tags               = (const int*)d_in[1];
    const int* mask               = (const int*)d_in[2];
    const float* start_tr         = (const float*)d_in[3];
    const float* end_tr           = (const float*)d_in[4];
    const float* trans            = (const float*)d_in[5];
    float* out                    = (float*)d_out;

    // scale numerator chunk count to available workspace
    const int nchunk = (ws_size >= (size_t)(BATCH * 4 + 32 * BATCH * 8 + 64)) ? 32 : 8;
    const int csz    = LSEQ / nchunk;

    float* denom = (float*)d_ws;                  // B floats
    float* part  = denom + BATCH;                 // nchunk*B floats
    int*   cnt   = (int*)(part + nchunk * BATCH); // nchunk*B ints

    crf_forward<<<256, 256, 0, stream>>>(emissions, mask, start_tr, end_tr, trans, denom);
    crf_score_partial<<<nchunk * BATCH / 256, 256, 0, stream>>>(
        emissions, tags, mask, trans, part, cnt, csz);
    crf_combine<<<1, 1024, 0, stream>>>(emissions, tags, start_tr, end_tr,
                                        part, cnt, denom, out, nchunk);
}